// Round 14
// baseline (1214.655 us; speedup 1.0000x reference)
//
#include <hip/hip_runtime.h>
#include <math.h>

// CV-photonic circuit: WIRES=4, LAYERS=2, CUTOFF=10, BATCH=2048.
// R14 = R13 + ds_read_b128/ds_write_b128 path for all mode-3 gate passes.
// Mode-3 fibers are contiguous (80 B); their fiber bases are multiples of
// 20 dwords -> only 8 distinct banks -> structural 8-way conflicts with 8-B
// accesses. b128 accesses hit the 8-cycle LDS floor with zero excess
// conflicts and halve the LDS instruction count for those 6 passes.

namespace {

constexpr int NTB = 1024;                // threads per state block (16 waves)
constexpr int SMEM_BYTES = 80384;        // state 80000 + uv 320 + red 64
constexpr double THETA = 0.7853981633974483096; // pi/4

struct cxf { float x, y; };
typedef float v2f __attribute__((ext_vector_type(2)));
typedef float v4f __attribute__((ext_vector_type(4)));

// ws float layout:
// [0,100)       V    (V[k*10+m]; used directly for the V^T gate)
// [100,200)     VT   (VT[k*10+i] = V[i][k]; used for the V gate)
// [200,1200)    Wt   (10 real 10x10, transposed: Wt[n*100+k*10+i]=W_n[i][k])
// [1200,5000)   BSt  cxf[19*100] zero-padded, transposed
// [5000,6600)   ULt  cxf[8*100]: f=0 (L0 UL0, VT-folded), f=4,5,6 (measure)
// [6600,9800)   stage cxf[16*100] raw S_lay (0..7) / D_lay (8..15)
// [9800,15800)  WUt  cxf[30*100]: WU_{b}[n] transposed, id=(b-1)*10+n
// [15872,...)   u    cxf[B*4*10] encoded per-(b,w) vectors
constexpr int U_OFF = 15872;

__device__ __forceinline__ cxf gen_squeeze_f(int i, int j, float zr, float zi){
  if (j == i+2){ float g = 0.5f*sqrtf((float)((i+1)*(i+2))); return {zr*g, -zi*g}; }
  if (i == j+2){ float g = 0.5f*sqrtf((float)((j+1)*(j+2))); return {-zr*g, -zi*g}; }
  return {0.f, 0.f};
}
__device__ __forceinline__ cxf gen_disp_f(int i, int j, float ar, float ai){
  if (i == j+1){ float g = sqrtf((float)i); return {ar*g, ai*g}; }
  if (j == i+1){ float g = sqrtf((float)j); return {-ar*g, ai*g}; }
  return {0.f, 0.f};
}

// Wave-cooperative fixed-schedule fp32 expm: result = exp(M), n x n (n<=10).
__device__ void expm_f32(bool act, int n, cxf* M, cxf* P, cxf* T, cxf* R, int lane){
  const int n2 = n*n;
  if (act){
    for (int e=lane; e<n2; e+=64){ M[e].x *= 0x1p-10f; M[e].y *= 0x1p-10f; }
    for (int e=lane; e<n2; e+=64){
      P[e] = M[e];
      cxf r = M[e];
      if (e % (n+1) == 0) r.x += 1.f;
      R[e] = r;
    }
  }
  __syncthreads();
  for (int t=2; t<=12; ++t){
    if (act){
      float inv = 1.f/(float)t;
      for (int e=lane; e<n2; e+=64){
        int i = e/n, j = e - i*n;
        float ax=0.f, ay=0.f;
        for (int k=0;k<n;k++){
          cxf p = P[i*n+k], m = M[k*n+j];
          ax += p.x*m.x - p.y*m.y;
          ay += p.x*m.y + p.y*m.x;
        }
        T[e] = {ax*inv, ay*inv};
      }
    }
    __syncthreads();
    { cxf* tmp = P; P = T; T = tmp; }
    if (act){ for (int e=lane; e<n2; e+=64){ R[e].x += P[e].x; R[e].y += P[e].y; } }
    __syncthreads();
  }
  for (int s=0; s<10; ++s){
    if (act){
      for (int e=lane; e<n2; e+=64){
        int i = e/n, j = e - i*n;
        float ax=0.f, ay=0.f;
        for (int k=0;k<n;k++){
          cxf p = R[i*n+k], q = R[k*n+j];
          ax += p.x*q.x - p.y*q.y;
          ay += p.x*q.y + p.y*q.x;
        }
        T[e] = {ax, ay};
      }
    }
    __syncthreads();
    { cxf* tmp = R; R = T; T = tmp; }
    __syncthreads();
  }
}

// ------------- Kernel A: 45 expm tasks fully parallel over 12 blocks -------
__global__ __launch_bounds__(256)
void gates_kernel(const float* __restrict__ dmag, const float* __restrict__ dphase,
                  const float* __restrict__ smag, const float* __restrict__ sphase,
                  float* __restrict__ wsf){
  __shared__ double lam[10];
  __shared__ float scr[4][4][200];      // [wave][buf] cxf[100]
  const int tid = threadIdx.x;
  const int wv = tid >> 6, lane = tid & 63, g = blockIdx.x;
  float* ws_V  = wsf;
  float* ws_VT = wsf + 100;
  float* ws_W  = wsf + 200;
  cxf* ws_BS   = (cxf*)(wsf + 1200);
  cxf* ws_stage= (cxf*)(wsf + 6600);

  if (tid < 10){
    double lo = -6.0, hi = 6.0;
    for (int it=0; it<80; ++it){
      double mid = 0.5*(lo+hi);
      int cnt = 0; double q = 1.0;
      for (int i=0;i<10;i++){
        q = -mid - (i ? (double)i/q : 0.0);
        if (fabs(q) < 1e-300) q = -1e-300;
        if (q < 0.0) cnt++;
      }
      if (cnt > tid) hi = mid; else lo = mid;
    }
    double x = 0.5*(lo+hi);
    double p[10];
    p[0] = 1.0; p[1] = x;
    for (int k=1;k<9;k++) p[k+1] = (x*p[k] - sqrt((double)k)*p[k-1]) * (1.0/sqrt((double)(k+1)));
    double nn=0.0; for (int k=0;k<10;k++) nn += p[k]*p[k];
    double inv = 1.0/sqrt(nn);
    lam[tid] = x;
    if (g == 0){
      for (int k=0;k<10;k++){
        float v = (float)(p[k]*inv);
        ws_V[k*10+tid]  = v;
        ws_VT[tid*10+k] = v;
      }
    }
  }
  __syncthreads();

  int t = g*4 + wv;
  bool act = (t < 45);
  int n = 10, bn = 0, ilo = 0;
  if (act && t >= 10 && t < 29){
    bn = t - 10; ilo = bn < 10 ? 0 : bn - 9;
    int ihi = bn < 10 ? bn : 9;
    n = ihi - ilo + 1;
  }
  cxf* M = (cxf*)scr[wv][0];
  cxf* P = (cxf*)scr[wv][1];
  cxf* T = (cxf*)scr[wv][2];
  cxf* R = (cxf*)scr[wv][3];
  if (act){
    if (t < 10){
      float l = (float)lam[t];   // Q = -0.5*(a - ad)
      for (int e=lane; e<100; e+=64){
        int i=e/10, j=e-10*i;
        float v = 0.f;
        if (j == i+1) v = -0.5f*l*sqrtf((float)(i+1));
        else if (i == j+1) v = 0.5f*l*sqrtf((float)i);
        M[e] = {v, 0.f};
      }
    } else if (t < 29){
      for (int e=lane; e<n*n; e+=64){
        int rr=e/n, c=e-n*rr;
        float v = 0.f;
        if (c == rr+1) v = (float)THETA*sqrtf((float)((ilo+rr+1)*(bn-ilo-rr)));
        else if (rr == c+1) v = (float)THETA*sqrtf((float)((ilo+c+1)*(bn-ilo-c)));
        M[e] = {0.f, v};
      }
    } else {
      int idx = t-29, kind = idx>>3, L=(idx>>2)&1, w=idx&3;
      float r_ = kind ? dmag[L*4+w]   : smag[L*4+w];
      float ph = kind ? dphase[L*4+w] : sphase[L*4+w];
      float zr = r_*cosf(ph), zi = r_*sinf(ph);
      for (int e=lane; e<100; e+=64){
        int i=e/10, j=e-10*i;
        M[e] = kind ? gen_disp_f(i,j,zr,zi) : gen_squeeze_f(i,j,zr,zi);
      }
    }
  }
  __syncthreads();
  expm_f32(act, n, M, P, T, R, lane);
  if (act){
    if (t < 10){
      for (int e=lane;e<100;e+=64){
        int i=e/10, j=e-10*i;
        ws_W[t*100 + j*10 + i] = R[e].x;   // transposed, real
      }
    } else if (t < 29){
      for (int e=lane;e<100;e+=64){
        int rr=e/10, c=e-10*rr;
        cxf o; o.x=0.f; o.y=0.f;
        if (rr < n && c < n) o = R[rr*n+c];
        ws_BS[bn*100 + c*10 + rr] = o;     // zero-padded + transposed
      }
    } else {
      int idx = t-29;
      for (int e=lane;e<100;e+=64) ws_stage[idx*100 + e] = R[e];
    }
  }
}

// ---- Kernel A2: UL products, VT fold, and WU_b[n] = W_n * UL_b fusion -----
__global__ __launch_bounds__(512)
void fuse_kernel(float* __restrict__ wsf){
  __shared__ cxf ulraw[8][100];          // raw UL[f] = D*S, [i*10+j]
  const int tid = threadIdx.x, wv = tid>>6, lane = tid&63;
  const cxf* stage = (const cxf*)(wsf + 6600);
  cxf* ws_UL = (cxf*)(wsf + 5000);
  cxf* ws_WU = (cxf*)(wsf + 9800);
  const float* V  = wsf;
  const float* Wt = wsf + 200;
  const cxf* Sm = stage + wv*100;
  const cxf* Dm = stage + (8+wv)*100;
  for (int e=lane; e<100; e+=64){
    int i=e/10, j=e-10*i;
    float ax=0.f, ay=0.f;
    for (int k=0;k<10;k++){
      cxf d=Dm[i*10+k], s=Sm[k*10+j];
      ax += d.x*s.x - d.y*s.y;
      ay += d.x*s.y + d.y*s.x;
    }
    ulraw[wv][e] = {ax, ay};
  }
  __syncthreads();
  // f=0 only: UL0 <- V^T * UL0 (carries L1's V0^T).
  cxf t0={0.f,0.f}, t1={0.f,0.f};
  if (wv == 0){
    {
      int e=lane, i=e/10, j=e-10*i;
      float ox=0.f, oy=0.f;
      for (int k=0;k<10;k++){ float v=V[k*10+i]; ox+=v*ulraw[0][k*10+j].x; oy+=v*ulraw[0][k*10+j].y; }
      t0 = {ox, oy};
    }
    if (lane+64 < 100){
      int e=lane+64, i=e/10, j=e-10*i;
      float ox=0.f, oy=0.f;
      for (int k=0;k<10;k++){ float v=V[k*10+i]; ox+=v*ulraw[0][k*10+j].x; oy+=v*ulraw[0][k*10+j].y; }
      t1 = {ox, oy};
    }
  }
  __syncthreads();
  if (wv == 0){
    ulraw[0][lane] = t0;
    if (lane+64 < 100) ulraw[0][lane+64] = t1;
  }
  __syncthreads();
  // Export ULt (transposed) for f in {0,4,5,6}
  for (int e=tid; e<400; e+=512){
    int fi = e/100, r = e-100*fi;
    int f = (fi==0) ? 0 : (3+fi);        // 0,4,5,6
    int i=r/10, j=r-10*i;
    ws_UL[f*100 + j*10 + i] = ulraw[f][i*10+j];
  }
  // Phase 2: WU_b[n] = W_n * ulraw[b], id=(b-1)*10+n, 30 tasks over 8 waves.
  for (int round=0; round<4; ++round){
    int id = round*8 + wv;
    if (id < 30){
      int b = 1 + id/10, n = id - (id/10)*10;
      const cxf* Ub = ulraw[b];
      for (int e=lane; e<100; e+=64){
        int i=e/10, j=e-10*i;
        float ax=0.f, ay=0.f;
        for (int k=0;k<10;k++){
          float w = Wt[n*100 + k*10 + i];   // W_n[i][k]
          ax += w*Ub[k*10+j].x;
          ay += w*Ub[k*10+j].y;
        }
        cxf o; o.x=ax; o.y=ay;
        ws_WU[id*100 + j*10 + i] = o;       // transposed
      }
    }
  }
}

// ------------- Kernel B: per-(b,w) encoding vector u = D*(S*e0), fp32 ------
__global__ __launch_bounds__(128)
void enc_kernel(const float* __restrict__ jets, const float* __restrict__ sscale,
                float* __restrict__ wsf){
  __shared__ float scr[2][4][200];
  __shared__ cxf col[10];
  __shared__ cxf uacc[10];
  const int tid = threadIdx.x, wv = tid>>6, lane = tid&63;
  const int blk = blockIdx.x, b = blk>>2, w = blk&3;

  float eta = jets[b*12 + w*3 + 0];
  float jph = jets[b*12 + w*3 + 1];
  float pt  = jets[b*12 + w*3 + 2];

  cxf* M = (cxf*)scr[wv][0];
  cxf* P = (cxf*)scr[wv][1];
  cxf* T = (cxf*)scr[wv][2];
  cxf* R = (cxf*)scr[wv][3];
  {
    float zr, zi;
    if (wv == 0){ float phs = pt*jph*0.5f; zr = eta*cosf(phs); zi = eta*sinf(phs); }
    else {
      double sc = 10.0/(1.0 + exp(-(double)sscale[0])) + 0.01;
      float mag = (float)sc*pt; zr = mag*cosf(eta); zi = mag*sinf(eta);
    }
    for (int e=lane; e<100; e+=64){
      int i=e/10, j=e-10*i;
      M[e] = wv ? gen_disp_f(i,j,zr,zi) : gen_squeeze_f(i,j,zr,zi);
    }
  }
  __syncthreads();
  expm_f32(true, 10, M, P, T, R, lane);
  cxf* Rs = (cxf*)scr[0][3];
  cxf* Rd = (cxf*)scr[1][3];
  if (tid < 10) col[tid] = Rs[tid*10];           // squeeze column 0
  __syncthreads();
  if (tid < 10){
    float ax=0.f, ay=0.f;
    for (int k=0;k<10;k++){
      cxf d = Rd[tid*10+k], c = col[k];
      ax += d.x*c.x - d.y*c.y;
      ay += d.x*c.y + d.y*c.x;
    }
    uacc[tid] = {ax, ay};
  }
  __syncthreads();
  if (tid < 10){
    float rx, ry;
    if (w == 0){
      rx = 0.f; ry = 0.f;
      for (int k=0;k<10;k++){
        float v = wsf[k*10 + tid];               // (V^T)[tid][k]
        rx += v*uacc[k].x;
        ry += v*uacc[k].y;
      }
    } else { rx = uacc[tid].x; ry = uacc[tid].y; }
    float* u_out = wsf + U_OFF + (b*40 + w*10 + tid)*2;
    u_out[0] = rx;
    u_out[1] = ry;
  }
}

// ---------------- Kernel C: the circuit, state-only LDS --------------------

#define DECL_ACCP \
  v2f a0={0.f,0.f}, a1={0.f,0.f}, a2={0.f,0.f}, a3={0.f,0.f}, a4={0.f,0.f}, \
      a5={0.f,0.f}, a6={0.f,0.f}, a7={0.f,0.f}, a8={0.f,0.f}, a9={0.f,0.f};

#define CKP(i) { v2f u = *(const v2f*)&U[kk+(i)]; \
  a##i = __builtin_elementwise_fma((v2f){u.x,u.x}, vv, a##i); \
  a##i = __builtin_elementwise_fma((v2f){-u.y,u.y}, vs, a##i); }
#define RKP(i) { float u = Mt[kk+(i)]; \
  a##i = __builtin_elementwise_fma((v2f){u,u}, vv, a##i); }
#define BKP(r) { v2f u = *(const v2f*)&Bt[kk+(r)]; \
  a##r = __builtin_elementwise_fma((v2f){u.x,u.x}, vv, a##r); \
  a##r = __builtin_elementwise_fma((v2f){-u.y,u.y}, vs, a##r); }

#define PSTORE(i) { *(v2f*)&S[base + (i)*sm] = a##i; }
#define PALLSTORE PSTORE(0) PSTORE(1) PSTORE(2) PSTORE(3) PSTORE(4) PSTORE(5) PSTORE(6) PSTORE(7) PSTORE(8) PSTORE(9)
#define BPSTORE(r) if ((r) < sz){ *(v2f*)&S[wadr] = a##r; wadr += ds; }
#define BPALLSTORE BPSTORE(0) BPSTORE(1) BPSTORE(2) BPSTORE(3) BPSTORE(4) BPSTORE(5) BPSTORE(6) BPSTORE(7) BPSTORE(8) BPSTORE(9)
// b128 pair store for contiguous (mode-3) fibers:
#define PST2(p,i,j) { v4f o; o.x=a##i.x; o.y=a##i.y; o.z=a##j.x; o.w=a##j.y; \
  *(v4f*)&S[base + 2*(p)] = o; }
#define PALLSTORE128 PST2(0,0,1) PST2(1,2,3) PST2(2,4,5) PST2(3,6,7) PST2(4,8,9)

__device__ __forceinline__ void apply1_c(cxf* S, const cxf* __restrict__ U, int m, int tid){
  const int sm = (m==0)?1000:((m==1)?100:((m==2)?10:1));
  const int r0 = (m==0)?1:0, r1=(m<=1)?2:1, r2=(m<=2)?3:2;
  const int s0 = (r0==0)?1000:((r0==1)?100:((r0==2)?10:1));
  const int s1 = (r1==0)?1000:((r1==1)?100:((r1==2)?10:1));
  const int s2 = (r2==0)?1000:((r2==1)?100:((r2==2)?10:1));
  int f = tid;
  if (f < 1000){
    int c0=f/100, rem=f-100*c0, c1=rem/10, c2=rem-10*c1;
    int base = c0*s0 + c1*s1 + c2*s2;
    DECL_ACCP
    #pragma unroll 2
    for (int k=0;k<10;k++){
      v2f vv = *(const v2f*)&S[base + k*sm];
      v2f vs = {vv.y, vv.x};
      int kk = k*10;
      CKP(0) CKP(1) CKP(2) CKP(3) CKP(4) CKP(5) CKP(6) CKP(7) CKP(8) CKP(9)
    }
    PALLSTORE
  }
}

__device__ __forceinline__ void apply1_r(cxf* S, const float* __restrict__ Mt, int m, int tid){
  const int sm = (m==0)?1000:((m==1)?100:((m==2)?10:1));
  const int r0 = (m==0)?1:0, r1=(m<=1)?2:1, r2=(m<=2)?3:2;
  const int s0 = (r0==0)?1000:((r0==1)?100:((r0==2)?10:1));
  const int s1 = (r1==0)?1000:((r1==1)?100:((r1==2)?10:1));
  const int s2 = (r2==0)?1000:((r2==1)?100:((r2==2)?10:1));
  int f = tid;
  if (f < 1000){
    int c0=f/100, rem=f-100*c0, c1=rem/10, c2=rem-10*c1;
    int base = c0*s0 + c1*s1 + c2*s2;
    DECL_ACCP
    #pragma unroll 2
    for (int k=0;k<10;k++){
      v2f vv = *(const v2f*)&S[base + k*sm];
      int kk = k*10;
      RKP(0) RKP(1) RKP(2) RKP(3) RKP(4) RKP(5) RKP(6) RKP(7) RKP(8) RKP(9)
    }
    PALLSTORE
  }
}

// Conditional real gate on m2 != 3 (selector on m1).
__device__ __forceinline__ void applyW(cxf* S, const float* __restrict__ Wall, int m1, int m2, int tid){
  const int sm  = (m2==0)?1000:((m2==1)?100:((m2==2)?10:1));
  const int sm1 = (m1==0)?1000:((m1==1)?100:((m1==2)?10:1));
  int ra=-1, rb=-1;
  for (int q=0;q<4;q++) if (q!=m1 && q!=m2){ if (ra<0) ra=q; else rb=q; }
  const int sa = (ra==0)?1000:((ra==1)?100:((ra==2)?10:1));
  const int sb = (rb==0)?1000:((rb==1)?100:((rb==2)?10:1));
  int f = tid;
  if (f < 1000){
    int n = f/100, rem = f-100*n, qa = rem/10, qb = rem-10*qa;
    int base = n*sm1 + qa*sa + qb*sb;
    const float* __restrict__ Mt = Wall + n*100;   // transposed W_n
    DECL_ACCP
    #pragma unroll 2
    for (int k=0;k<10;k++){
      v2f vv = *(const v2f*)&S[base + k*sm];
      int kk = k*10;
      RKP(0) RKP(1) RKP(2) RKP(3) RKP(4) RKP(5) RKP(6) RKP(7) RKP(8) RKP(9)
    }
    PALLSTORE
  }
}

// Conditional REAL gate on mode 3 (contiguous fiber): b128 loads/stores.
__device__ __forceinline__ void applyW_m3(cxf* S, const float* __restrict__ Wall, int m1, int tid){
  const int sm1 = (m1==0)?1000:((m1==1)?100:10);
  int ra=-1, rb=-1;
  for (int q=0;q<3;q++) if (q!=m1){ if (ra<0) ra=q; else rb=q; }
  const int sa = (ra==0)?1000:((ra==1)?100:10);
  const int sb = (rb==1)?100:10;
  int f = tid;
  if (f < 1000){
    int n = f/100, rem = f-100*n, qa = rem/10, qb = rem-10*qa;
    int base = n*sm1 + qa*sa + qb*sb;      // multiple of 10 -> 16B aligned
    const float* __restrict__ Mt = Wall + n*100;
    DECL_ACCP
    #pragma unroll
    for (int kp=0; kp<5; ++kp){
      v4f qv = *(const v4f*)&S[base + 2*kp];
      { v2f vv = {qv.x, qv.y}; int kk = 20*kp;
        RKP(0) RKP(1) RKP(2) RKP(3) RKP(4) RKP(5) RKP(6) RKP(7) RKP(8) RKP(9) }
      { v2f vv = {qv.z, qv.w}; int kk = 20*kp + 10;
        RKP(0) RKP(1) RKP(2) RKP(3) RKP(4) RKP(5) RKP(6) RKP(7) RKP(8) RKP(9) }
    }
    PALLSTORE128
  }
}

// Conditional COMPLEX gate on m2 (selector on mode 0): WU_b[n] = W_n*UL_b.
__device__ __forceinline__ void applyWU(cxf* S, const cxf* __restrict__ WUall, int m2, int tid){
  const int sm = (m2==1)?100:10;         // m2 in {1,2}
  const int ra = (m2==1)?2:1;
  const int sa = (ra==1)?100:10;
  const int sb = 1;                       // mode 3 remains
  int f = tid;
  if (f < 1000){
    int n = f/100, rem = f-100*n, qa = rem/10, qb = rem-10*qa;
    int base = n*1000 + qa*sa + qb*sb;
    const cxf* __restrict__ U = WUall + n*100;     // transposed complex
    DECL_ACCP
    #pragma unroll 2
    for (int k=0;k<10;k++){
      v2f vv = *(const v2f*)&S[base + k*sm];
      v2f vs = {vv.y, vv.x};
      int kk = k*10;
      CKP(0) CKP(1) CKP(2) CKP(3) CKP(4) CKP(5) CKP(6) CKP(7) CKP(8) CKP(9)
    }
    PALLSTORE
  }
}

// Conditional COMPLEX gate on mode 3 (selector mode 0): b128 path.
__device__ __forceinline__ void applyWU_m3(cxf* S, const cxf* __restrict__ WUall, int tid){
  int f = tid;
  if (f < 1000){
    int n = f/100, rem = f-100*n, qa = rem/10, qb = rem-10*qa;
    int base = n*1000 + qa*100 + qb*10;
    const cxf* __restrict__ U = WUall + n*100;
    DECL_ACCP
    #pragma unroll
    for (int kp=0; kp<5; ++kp){
      v4f qv = *(const v4f*)&S[base + 2*kp];
      { v2f vv = {qv.x, qv.y}; v2f vs = {vv.y, vv.x}; int kk = 20*kp;
        CKP(0) CKP(1) CKP(2) CKP(3) CKP(4) CKP(5) CKP(6) CKP(7) CKP(8) CKP(9) }
      { v2f vv = {qv.z, qv.w}; v2f vs = {vv.y, vv.x}; int kk = 20*kp + 10;
        CKP(0) CKP(1) CKP(2) CKP(3) CKP(4) CKP(5) CKP(6) CKP(7) CKP(8) CKP(9) }
    }
    PALLSTORE128
  }
}

// Read-only measure pass: returns sum_i i*|(U v)_i|^2 over this thread's fiber.
__device__ __forceinline__ float measure1(const cxf* S, const cxf* __restrict__ U, int m, int tid){
  const int sm = (m==0)?1000:((m==1)?100:10);
  const int r0 = (m==0)?1:0, r1=(m<=1)?2:1;
  const int s0 = (r0==0)?1000:100;
  const int s1 = (r1==1)?100:10;
  const int s2 = 1;
  int f = tid;
  float s = 0.f;
  if (f < 1000){
    int c0=f/100, rem=f-100*c0, c1=rem/10, c2=rem-10*c1;
    int base = c0*s0 + c1*s1 + c2*s2;
    DECL_ACCP
    #pragma unroll 2
    for (int k=0;k<10;k++){
      v2f vv = *(const v2f*)&S[base + k*sm];
      v2f vs = {vv.y, vv.x};
      int kk = k*10;
      CKP(0) CKP(1) CKP(2) CKP(3) CKP(4) CKP(5) CKP(6) CKP(7) CKP(8) CKP(9)
    }
    float p;
    p = a1.x*a1.x + a1.y*a1.y; s += 1.f*p;
    p = a2.x*a2.x + a2.y*a2.y; s += 2.f*p;
    p = a3.x*a3.x + a3.y*a3.y; s += 3.f*p;
    p = a4.x*a4.x + a4.y*a4.y; s += 4.f*p;
    p = a5.x*a5.x + a5.y*a5.y; s += 5.f*p;
    p = a6.x*a6.x + a6.y*a6.y; s += 6.f*p;
    p = a7.x*a7.x + a7.y*a7.y; s += 7.f*p;
    p = a8.x*a8.x + a8.y*a8.y; s += 8.f*p;
    p = a9.x*a9.x + a9.y*a9.y; s += 9.f*p;
  }
  return s;
}

__device__ __forceinline__ void applyBS(cxf* S, const cxf* __restrict__ BSp, int m1, int m2, int tid){
  int ra=-1, rb=-1;
  for (int q=0;q<4;q++) if (q!=m1 && q!=m2){ if (ra<0) ra=q; else rb=q; }
  const int sa = (ra==0)?1000:((ra==1)?100:((ra==2)?10:1));
  const int sb = (rb==0)?1000:((rb==1)?100:((rb==2)?10:1));
  const int s1 = (m1==0)?1000:((m1==1)?100:((m1==2)?10:1));
  const int s2 = (m2==0)?1000:((m2==1)?100:((m2==2)?10:1));
  const int ds = s1 - s2;
  #pragma unroll 1
  for (int w0=0; w0<2048; w0+=NTB){
    int it = w0 + tid;
    if (it < 1900){
      int bn = it/100, rest = it-100*bn;
      int ilo = bn<10?0:bn-9, ihi = bn<10?bn:9, sz = ihi-ilo+1;
      int ca = rest/10, cb = rest-10*ca;
      int base = ca*sa + cb*sb;
      const cxf* __restrict__ Bt = BSp + bn*100;   // transposed
      DECL_ACCP
      int radr = base + ilo*s1 + (bn-ilo)*s2;
      int kk = 0;
      #pragma unroll 1
      for (int c=0;c<sz;c++){
        v2f vv = *(const v2f*)&S[radr];
        v2f vs = {vv.y, vv.x};
        BKP(0) BKP(1) BKP(2) BKP(3) BKP(4) BKP(5) BKP(6) BKP(7) BKP(8) BKP(9)
        radr += ds; kk += 10;
      }
      int wadr = base + ilo*s1 + (bn-ilo)*s2;
      BPALLSTORE
    }
  }
}

__global__ __launch_bounds__(NTB)
__attribute__((amdgpu_waves_per_eu(8)))
void state_kernel(const float* __restrict__ wd, const float* __restrict__ bd,
                  const float* __restrict__ wsf, float* __restrict__ out){
  extern __shared__ __align__(16) char smem[];
  cxf* S    = (cxf*)smem;                 // 10000 cxf (80000 B)
  cxf* uv   = (cxf*)(smem + 80000);       // 4*10 encoding vectors
  float* red = (float*)(smem + 80320);    // 16

  const float* __restrict__ V   = wsf;            // for V^T gate
  const float* __restrict__ VT  = wsf + 100;      // for V gate
  const float* __restrict__ W   = wsf + 200;
  const cxf*   __restrict__ BSm = (const cxf*)(wsf + 1200);
  const cxf*   __restrict__ UL  = (const cxf*)(wsf + 5000);
  const cxf*   __restrict__ WU  = (const cxf*)(wsf + 9800);
  const cxf*   __restrict__ uw  = (const cxf*)(wsf + U_OFF);

  const int tid = threadIdx.x, wv = tid>>6, lane = tid&63;
  const int b = blockIdx.x;

  if (tid < 40) uv[tid] = uw[b*40 + tid];
  __syncthreads();

  // Init: product state S = u0 (x) u1 (x) u2 (x) u3  (L0's V0^T folded in u0)
  for (int e=tid; e<10000; e+=NTB){
    int c0=e/1000, r_=e-1000*c0, c1=r_/100, r2_=r_-100*c1, c2=r2_/10, c3=r2_-10*c2;
    cxf A = uv[c0], B = uv[10+c1], C = uv[20+c2], D = uv[30+c3];
    float pr = A.x*B.x - A.y*B.y, pi = A.x*B.y + A.y*B.x;
    float qr = pr*C.x - pi*C.y,  qi = pr*C.y + pi*C.x;
    cxf o; o.x = qr*D.x - qi*D.y; o.y = qr*D.y + qi*D.x;
    S[e] = o;
  }
  __syncthreads();

  // ---------------- Layer 0 ----------------
  applyW(S, W, 0, 1, tid); __syncthreads();
  applyW(S, W, 0, 2, tid); __syncthreads();
  applyW_m3(S, W, 0, tid); __syncthreads();
  apply1_r(S, VT, 0, tid); __syncthreads();      // V0
  apply1_r(S, V, 1, tid);  __syncthreads();      // V1^T
  applyW(S, W, 1, 2, tid); __syncthreads();
  applyW_m3(S, W, 1, tid); __syncthreads();
  apply1_r(S, VT, 1, tid); __syncthreads();      // V1
  apply1_r(S, V, 2, tid);  __syncthreads();      // V2^T
  applyW_m3(S, W, 2, tid); __syncthreads();
  apply1_r(S, VT, 2, tid); __syncthreads();      // V2
  applyBS(S, BSm, 0, 1, tid); __syncthreads();
  applyBS(S, BSm, 1, 2, tid); __syncthreads();
  applyBS(S, BSm, 2, 3, tid); __syncthreads();
  applyBS(S, BSm, 3, 0, tid); __syncthreads();
  apply1_c(S, UL, 0, tid); __syncthreads();      // UL0_L0 (carries L1's V0^T)

  // ---------------- Layer 1 ----------------
  applyWU(S, WU,        1, tid); __syncthreads();
  applyWU(S, WU + 1000, 2, tid); __syncthreads();
  applyWU_m3(S, WU + 2000, tid); __syncthreads();
  apply1_r(S, VT, 0, tid); __syncthreads();      // V0
  apply1_r(S, V, 1, tid);  __syncthreads();      // V1^T
  applyW(S, W, 1, 2, tid); __syncthreads();
  applyW_m3(S, W, 1, tid); __syncthreads();
  apply1_r(S, VT, 1, tid); __syncthreads();      // V1
  apply1_r(S, V, 2, tid);  __syncthreads();      // V2^T
  applyW_m3(S, W, 2, tid); __syncthreads();
  apply1_r(S, VT, 2, tid); __syncthreads();      // V2
  applyBS(S, BSm, 0, 1, tid); __syncthreads();
  applyBS(S, BSm, 1, 2, tid); __syncthreads();
  applyBS(S, BSm, 2, 3, tid); __syncthreads();
  applyBS(S, BSm, 3, 0, tid); __syncthreads();

  // Fused measurement (UL[L1,3] dropped; read-only passes, no barriers).
  float w0 = wd[0], w1 = wd[1], w2 = wd[2];
  float acc = 0.f;
  acc += w0 * measure1(S, UL + 400, 0, tid);
  acc += w1 * measure1(S, UL + 500, 1, tid);
  acc += w2 * measure1(S, UL + 600, 2, tid);

  for (int off=32; off; off>>=1) acc += __shfl_down(acc, off, 64);
  if (lane == 0) red[wv] = acc;
  __syncthreads();
  if (tid == 0){
    float s = 0.f;
    for (int i=0;i<16;i++) s += red[i];
    out[b] = s + bd[0];
  }
}

} // anonymous namespace

extern "C" void kernel_launch(void* const* d_in, const int* in_sizes, int n_in,
                              void* d_out, int out_size, void* d_ws, size_t ws_size,
                              hipStream_t stream){
  const float* jets   = (const float*)d_in[0];
  const float* sscale = (const float*)d_in[1];
  const float* dmag   = (const float*)d_in[2];
  const float* dphase = (const float*)d_in[3];
  const float* smag   = (const float*)d_in[4];
  const float* sphase = (const float*)d_in[5];
  const float* wd     = (const float*)d_in[6];
  const float* bd     = (const float*)d_in[7];
  float* out = (float*)d_out;
  float* wsf = (float*)d_ws;
  int B = in_sizes[0] / 12;

  (void)hipFuncSetAttribute(reinterpret_cast<const void*>(&state_kernel),
                            hipFuncAttributeMaxDynamicSharedMemorySize, SMEM_BYTES);

  gates_kernel<<<12, 256, 0, stream>>>(dmag, dphase, smag, sphase, wsf);
  fuse_kernel<<<1, 512, 0, stream>>>(wsf);
  enc_kernel<<<B*4, 128, 0, stream>>>(jets, sscale, wsf);
  state_kernel<<<B, NTB, SMEM_BYTES, stream>>>(wd, bd, wsf, out);
}

// Round 15
// 1098.304 us; speedup vs baseline: 1.1059x; 1.1059x over previous
//
#include <hip/hip_runtime.h>
#include <math.h>

// CV-photonic circuit: WIRES=4, LAYERS=2, CUTOFF=10, BATCH=2048.
// R15 = R13 verbatim (best: 1094.7us total / 951us state). R14's b128
// mode-3 path re-introduced scratch spill (WRITE 64KB->339MB) and regressed;
// reverted. R13 structure: state-only LDS (2 blocks/CU, 32 waves), pk-fma
// gate bodies (named v2f accumulators), CX eigen-factorization with V^T..V
// cancellation, L0-UL->L1-W fusion (WU), dropped UL[L1,3], fused measurement.

namespace {

constexpr int NTB = 1024;                // threads per state block (16 waves)
constexpr int SMEM_BYTES = 80384;        // state 80000 + uv 320 + red 64
constexpr double THETA = 0.7853981633974483096; // pi/4

struct cxf { float x, y; };
typedef float v2f __attribute__((ext_vector_type(2)));

// ws float layout:
// [0,100)       V    (V[k*10+m]; used directly for the V^T gate)
// [100,200)     VT   (VT[k*10+i] = V[i][k]; used for the V gate)
// [200,1200)    Wt   (10 real 10x10, transposed: Wt[n*100+k*10+i]=W_n[i][k])
// [1200,5000)   BSt  cxf[19*100] zero-padded, transposed
// [5000,6600)   ULt  cxf[8*100]: f=0 (L0 UL0, VT-folded), f=4,5,6 (measure)
// [6600,9800)   stage cxf[16*100] raw S_lay (0..7) / D_lay (8..15)
// [9800,15800)  WUt  cxf[30*100]: WU_{b}[n] transposed, id=(b-1)*10+n
// [15872,...)   u    cxf[B*4*10] encoded per-(b,w) vectors
constexpr int U_OFF = 15872;

__device__ __forceinline__ cxf gen_squeeze_f(int i, int j, float zr, float zi){
  if (j == i+2){ float g = 0.5f*sqrtf((float)((i+1)*(i+2))); return {zr*g, -zi*g}; }
  if (i == j+2){ float g = 0.5f*sqrtf((float)((j+1)*(j+2))); return {-zr*g, -zi*g}; }
  return {0.f, 0.f};
}
__device__ __forceinline__ cxf gen_disp_f(int i, int j, float ar, float ai){
  if (i == j+1){ float g = sqrtf((float)i); return {ar*g, ai*g}; }
  if (j == i+1){ float g = sqrtf((float)j); return {-ar*g, ai*g}; }
  return {0.f, 0.f};
}

// Wave-cooperative fixed-schedule fp32 expm: result = exp(M), n x n (n<=10).
__device__ void expm_f32(bool act, int n, cxf* M, cxf* P, cxf* T, cxf* R, int lane){
  const int n2 = n*n;
  if (act){
    for (int e=lane; e<n2; e+=64){ M[e].x *= 0x1p-10f; M[e].y *= 0x1p-10f; }
    for (int e=lane; e<n2; e+=64){
      P[e] = M[e];
      cxf r = M[e];
      if (e % (n+1) == 0) r.x += 1.f;
      R[e] = r;
    }
  }
  __syncthreads();
  for (int t=2; t<=12; ++t){
    if (act){
      float inv = 1.f/(float)t;
      for (int e=lane; e<n2; e+=64){
        int i = e/n, j = e - i*n;
        float ax=0.f, ay=0.f;
        for (int k=0;k<n;k++){
          cxf p = P[i*n+k], m = M[k*n+j];
          ax += p.x*m.x - p.y*m.y;
          ay += p.x*m.y + p.y*m.x;
        }
        T[e] = {ax*inv, ay*inv};
      }
    }
    __syncthreads();
    { cxf* tmp = P; P = T; T = tmp; }
    if (act){ for (int e=lane; e<n2; e+=64){ R[e].x += P[e].x; R[e].y += P[e].y; } }
    __syncthreads();
  }
  for (int s=0; s<10; ++s){
    if (act){
      for (int e=lane; e<n2; e+=64){
        int i = e/n, j = e - i*n;
        float ax=0.f, ay=0.f;
        for (int k=0;k<n;k++){
          cxf p = R[i*n+k], q = R[k*n+j];
          ax += p.x*q.x - p.y*q.y;
          ay += p.x*q.y + p.y*q.x;
        }
        T[e] = {ax, ay};
      }
    }
    __syncthreads();
    { cxf* tmp = R; R = T; T = tmp; }
    __syncthreads();
  }
}

// ------------- Kernel A: 45 expm tasks fully parallel over 12 blocks -------
__global__ __launch_bounds__(256)
void gates_kernel(const float* __restrict__ dmag, const float* __restrict__ dphase,
                  const float* __restrict__ smag, const float* __restrict__ sphase,
                  float* __restrict__ wsf){
  __shared__ double lam[10];
  __shared__ float scr[4][4][200];      // [wave][buf] cxf[100]
  const int tid = threadIdx.x;
  const int wv = tid >> 6, lane = tid & 63, g = blockIdx.x;
  float* ws_V  = wsf;
  float* ws_VT = wsf + 100;
  float* ws_W  = wsf + 200;
  cxf* ws_BS   = (cxf*)(wsf + 1200);
  cxf* ws_stage= (cxf*)(wsf + 6600);

  if (tid < 10){
    double lo = -6.0, hi = 6.0;
    for (int it=0; it<80; ++it){
      double mid = 0.5*(lo+hi);
      int cnt = 0; double q = 1.0;
      for (int i=0;i<10;i++){
        q = -mid - (i ? (double)i/q : 0.0);
        if (fabs(q) < 1e-300) q = -1e-300;
        if (q < 0.0) cnt++;
      }
      if (cnt > tid) hi = mid; else lo = mid;
    }
    double x = 0.5*(lo+hi);
    double p[10];
    p[0] = 1.0; p[1] = x;
    for (int k=1;k<9;k++) p[k+1] = (x*p[k] - sqrt((double)k)*p[k-1]) * (1.0/sqrt((double)(k+1)));
    double nn=0.0; for (int k=0;k<10;k++) nn += p[k]*p[k];
    double inv = 1.0/sqrt(nn);
    lam[tid] = x;
    if (g == 0){
      for (int k=0;k<10;k++){
        float v = (float)(p[k]*inv);
        ws_V[k*10+tid]  = v;
        ws_VT[tid*10+k] = v;
      }
    }
  }
  __syncthreads();

  int t = g*4 + wv;
  bool act = (t < 45);
  int n = 10, bn = 0, ilo = 0;
  if (act && t >= 10 && t < 29){
    bn = t - 10; ilo = bn < 10 ? 0 : bn - 9;
    int ihi = bn < 10 ? bn : 9;
    n = ihi - ilo + 1;
  }
  cxf* M = (cxf*)scr[wv][0];
  cxf* P = (cxf*)scr[wv][1];
  cxf* T = (cxf*)scr[wv][2];
  cxf* R = (cxf*)scr[wv][3];
  if (act){
    if (t < 10){
      float l = (float)lam[t];   // Q = -0.5*(a - ad)
      for (int e=lane; e<100; e+=64){
        int i=e/10, j=e-10*i;
        float v = 0.f;
        if (j == i+1) v = -0.5f*l*sqrtf((float)(i+1));
        else if (i == j+1) v = 0.5f*l*sqrtf((float)i);
        M[e] = {v, 0.f};
      }
    } else if (t < 29){
      for (int e=lane; e<n*n; e+=64){
        int rr=e/n, c=e-n*rr;
        float v = 0.f;
        if (c == rr+1) v = (float)THETA*sqrtf((float)((ilo+rr+1)*(bn-ilo-rr)));
        else if (rr == c+1) v = (float)THETA*sqrtf((float)((ilo+c+1)*(bn-ilo-c)));
        M[e] = {0.f, v};
      }
    } else {
      int idx = t-29, kind = idx>>3, L=(idx>>2)&1, w=idx&3;
      float r_ = kind ? dmag[L*4+w]   : smag[L*4+w];
      float ph = kind ? dphase[L*4+w] : sphase[L*4+w];
      float zr = r_*cosf(ph), zi = r_*sinf(ph);
      for (int e=lane; e<100; e+=64){
        int i=e/10, j=e-10*i;
        M[e] = kind ? gen_disp_f(i,j,zr,zi) : gen_squeeze_f(i,j,zr,zi);
      }
    }
  }
  __syncthreads();
  expm_f32(act, n, M, P, T, R, lane);
  if (act){
    if (t < 10){
      for (int e=lane;e<100;e+=64){
        int i=e/10, j=e-10*i;
        ws_W[t*100 + j*10 + i] = R[e].x;   // transposed, real
      }
    } else if (t < 29){
      for (int e=lane;e<100;e+=64){
        int rr=e/10, c=e-10*rr;
        cxf o; o.x=0.f; o.y=0.f;
        if (rr < n && c < n) o = R[rr*n+c];
        ws_BS[bn*100 + c*10 + rr] = o;     // zero-padded + transposed
      }
    } else {
      int idx = t-29;
      for (int e=lane;e<100;e+=64) ws_stage[idx*100 + e] = R[e];
    }
  }
}

// ---- Kernel A2: UL products, VT fold, and WU_b[n] = W_n * UL_b fusion -----
__global__ __launch_bounds__(512)
void fuse_kernel(float* __restrict__ wsf){
  __shared__ cxf ulraw[8][100];          // raw UL[f] = D*S, [i*10+j]
  const int tid = threadIdx.x, wv = tid>>6, lane = tid&63;
  const cxf* stage = (const cxf*)(wsf + 6600);
  cxf* ws_UL = (cxf*)(wsf + 5000);
  cxf* ws_WU = (cxf*)(wsf + 9800);
  const float* V  = wsf;
  const float* Wt = wsf + 200;
  const cxf* Sm = stage + wv*100;
  const cxf* Dm = stage + (8+wv)*100;
  for (int e=lane; e<100; e+=64){
    int i=e/10, j=e-10*i;
    float ax=0.f, ay=0.f;
    for (int k=0;k<10;k++){
      cxf d=Dm[i*10+k], s=Sm[k*10+j];
      ax += d.x*s.x - d.y*s.y;
      ay += d.x*s.y + d.y*s.x;
    }
    ulraw[wv][e] = {ax, ay};
  }
  __syncthreads();
  // f=0 only: UL0 <- V^T * UL0 (carries L1's V0^T).
  cxf t0={0.f,0.f}, t1={0.f,0.f};
  if (wv == 0){
    {
      int e=lane, i=e/10, j=e-10*i;
      float ox=0.f, oy=0.f;
      for (int k=0;k<10;k++){ float v=V[k*10+i]; ox+=v*ulraw[0][k*10+j].x; oy+=v*ulraw[0][k*10+j].y; }
      t0 = {ox, oy};
    }
    if (lane+64 < 100){
      int e=lane+64, i=e/10, j=e-10*i;
      float ox=0.f, oy=0.f;
      for (int k=0;k<10;k++){ float v=V[k*10+i]; ox+=v*ulraw[0][k*10+j].x; oy+=v*ulraw[0][k*10+j].y; }
      t1 = {ox, oy};
    }
  }
  __syncthreads();
  if (wv == 0){
    ulraw[0][lane] = t0;
    if (lane+64 < 100) ulraw[0][lane+64] = t1;
  }
  __syncthreads();
  // Export ULt (transposed) for f in {0,4,5,6}
  for (int e=tid; e<400; e+=512){
    int fi = e/100, r = e-100*fi;
    int f = (fi==0) ? 0 : (3+fi);        // 0,4,5,6
    int i=r/10, j=r-10*i;
    ws_UL[f*100 + j*10 + i] = ulraw[f][i*10+j];
  }
  // Phase 2: WU_b[n] = W_n * ulraw[b], id=(b-1)*10+n, 30 tasks over 8 waves.
  for (int round=0; round<4; ++round){
    int id = round*8 + wv;
    if (id < 30){
      int b = 1 + id/10, n = id - (id/10)*10;
      const cxf* Ub = ulraw[b];
      for (int e=lane; e<100; e+=64){
        int i=e/10, j=e-10*i;
        float ax=0.f, ay=0.f;
        for (int k=0;k<10;k++){
          float w = Wt[n*100 + k*10 + i];   // W_n[i][k]
          ax += w*Ub[k*10+j].x;
          ay += w*Ub[k*10+j].y;
        }
        cxf o; o.x=ax; o.y=ay;
        ws_WU[id*100 + j*10 + i] = o;       // transposed
      }
    }
  }
}

// ------------- Kernel B: per-(b,w) encoding vector u = D*(S*e0), fp32 ------
__global__ __launch_bounds__(128)
void enc_kernel(const float* __restrict__ jets, const float* __restrict__ sscale,
                float* __restrict__ wsf){
  __shared__ float scr[2][4][200];
  __shared__ cxf col[10];
  __shared__ cxf uacc[10];
  const int tid = threadIdx.x, wv = tid>>6, lane = tid&63;
  const int blk = blockIdx.x, b = blk>>2, w = blk&3;

  float eta = jets[b*12 + w*3 + 0];
  float jph = jets[b*12 + w*3 + 1];
  float pt  = jets[b*12 + w*3 + 2];

  cxf* M = (cxf*)scr[wv][0];
  cxf* P = (cxf*)scr[wv][1];
  cxf* T = (cxf*)scr[wv][2];
  cxf* R = (cxf*)scr[wv][3];
  {
    float zr, zi;
    if (wv == 0){ float phs = pt*jph*0.5f; zr = eta*cosf(phs); zi = eta*sinf(phs); }
    else {
      double sc = 10.0/(1.0 + exp(-(double)sscale[0])) + 0.01;
      float mag = (float)sc*pt; zr = mag*cosf(eta); zi = mag*sinf(eta);
    }
    for (int e=lane; e<100; e+=64){
      int i=e/10, j=e-10*i;
      M[e] = wv ? gen_disp_f(i,j,zr,zi) : gen_squeeze_f(i,j,zr,zi);
    }
  }
  __syncthreads();
  expm_f32(true, 10, M, P, T, R, lane);
  cxf* Rs = (cxf*)scr[0][3];
  cxf* Rd = (cxf*)scr[1][3];
  if (tid < 10) col[tid] = Rs[tid*10];           // squeeze column 0
  __syncthreads();
  if (tid < 10){
    float ax=0.f, ay=0.f;
    for (int k=0;k<10;k++){
      cxf d = Rd[tid*10+k], c = col[k];
      ax += d.x*c.x - d.y*c.y;
      ay += d.x*c.y + d.y*c.x;
    }
    uacc[tid] = {ax, ay};
  }
  __syncthreads();
  if (tid < 10){
    float rx, ry;
    if (w == 0){
      rx = 0.f; ry = 0.f;
      for (int k=0;k<10;k++){
        float v = wsf[k*10 + tid];               // (V^T)[tid][k]
        rx += v*uacc[k].x;
        ry += v*uacc[k].y;
      }
    } else { rx = uacc[tid].x; ry = uacc[tid].y; }
    float* u_out = wsf + U_OFF + (b*40 + w*10 + tid)*2;
    u_out[0] = rx;
    u_out[1] = ry;
  }
}

// ---------------- Kernel C: the circuit, state-only LDS --------------------

#define DECL_ACCP \
  v2f a0={0.f,0.f}, a1={0.f,0.f}, a2={0.f,0.f}, a3={0.f,0.f}, a4={0.f,0.f}, \
      a5={0.f,0.f}, a6={0.f,0.f}, a7={0.f,0.f}, a8={0.f,0.f}, a9={0.f,0.f};

#define CKP(i) { v2f u = *(const v2f*)&U[kk+(i)]; \
  a##i = __builtin_elementwise_fma((v2f){u.x,u.x}, vv, a##i); \
  a##i = __builtin_elementwise_fma((v2f){-u.y,u.y}, vs, a##i); }
#define RKP(i) { float u = Mt[kk+(i)]; \
  a##i = __builtin_elementwise_fma((v2f){u,u}, vv, a##i); }
#define BKP(r) { v2f u = *(const v2f*)&Bt[kk+(r)]; \
  a##r = __builtin_elementwise_fma((v2f){u.x,u.x}, vv, a##r); \
  a##r = __builtin_elementwise_fma((v2f){-u.y,u.y}, vs, a##r); }

#define PSTORE(i) { *(v2f*)&S[base + (i)*sm] = a##i; }
#define PALLSTORE PSTORE(0) PSTORE(1) PSTORE(2) PSTORE(3) PSTORE(4) PSTORE(5) PSTORE(6) PSTORE(7) PSTORE(8) PSTORE(9)
#define BPSTORE(r) if ((r) < sz){ *(v2f*)&S[wadr] = a##r; wadr += ds; }
#define BPALLSTORE BPSTORE(0) BPSTORE(1) BPSTORE(2) BPSTORE(3) BPSTORE(4) BPSTORE(5) BPSTORE(6) BPSTORE(7) BPSTORE(8) BPSTORE(9)

__device__ __forceinline__ void apply1_c(cxf* S, const cxf* __restrict__ U, int m, int tid){
  const int sm = (m==0)?1000:((m==1)?100:((m==2)?10:1));
  const int r0 = (m==0)?1:0, r1=(m<=1)?2:1, r2=(m<=2)?3:2;
  const int s0 = (r0==0)?1000:((r0==1)?100:((r0==2)?10:1));
  const int s1 = (r1==0)?1000:((r1==1)?100:((r1==2)?10:1));
  const int s2 = (r2==0)?1000:((r2==1)?100:((r2==2)?10:1));
  int f = tid;
  if (f < 1000){
    int c0=f/100, rem=f-100*c0, c1=rem/10, c2=rem-10*c1;
    int base = c0*s0 + c1*s1 + c2*s2;
    DECL_ACCP
    #pragma unroll 2
    for (int k=0;k<10;k++){
      v2f vv = *(const v2f*)&S[base + k*sm];
      v2f vs = {vv.y, vv.x};
      int kk = k*10;
      CKP(0) CKP(1) CKP(2) CKP(3) CKP(4) CKP(5) CKP(6) CKP(7) CKP(8) CKP(9)
    }
    PALLSTORE
  }
}

__device__ __forceinline__ void apply1_r(cxf* S, const float* __restrict__ Mt, int m, int tid){
  const int sm = (m==0)?1000:((m==1)?100:((m==2)?10:1));
  const int r0 = (m==0)?1:0, r1=(m<=1)?2:1, r2=(m<=2)?3:2;
  const int s0 = (r0==0)?1000:((r0==1)?100:((r0==2)?10:1));
  const int s1 = (r1==0)?1000:((r1==1)?100:((r1==2)?10:1));
  const int s2 = (r2==0)?1000:((r2==1)?100:((r2==2)?10:1));
  int f = tid;
  if (f < 1000){
    int c0=f/100, rem=f-100*c0, c1=rem/10, c2=rem-10*c1;
    int base = c0*s0 + c1*s1 + c2*s2;
    DECL_ACCP
    #pragma unroll 2
    for (int k=0;k<10;k++){
      v2f vv = *(const v2f*)&S[base + k*sm];
      int kk = k*10;
      RKP(0) RKP(1) RKP(2) RKP(3) RKP(4) RKP(5) RKP(6) RKP(7) RKP(8) RKP(9)
    }
    PALLSTORE
  }
}

__device__ __forceinline__ void applyW(cxf* S, const float* __restrict__ Wall, int m1, int m2, int tid){
  const int sm  = (m2==0)?1000:((m2==1)?100:((m2==2)?10:1));
  const int sm1 = (m1==0)?1000:((m1==1)?100:((m1==2)?10:1));
  int ra=-1, rb=-1;
  for (int q=0;q<4;q++) if (q!=m1 && q!=m2){ if (ra<0) ra=q; else rb=q; }
  const int sa = (ra==0)?1000:((ra==1)?100:((ra==2)?10:1));
  const int sb = (rb==0)?1000:((rb==1)?100:((rb==2)?10:1));
  int f = tid;
  if (f < 1000){
    int n = f/100, rem = f-100*n, qa = rem/10, qb = rem-10*qa;
    int base = n*sm1 + qa*sa + qb*sb;
    const float* __restrict__ Mt = Wall + n*100;   // transposed W_n
    DECL_ACCP
    #pragma unroll 2
    for (int k=0;k<10;k++){
      v2f vv = *(const v2f*)&S[base + k*sm];
      int kk = k*10;
      RKP(0) RKP(1) RKP(2) RKP(3) RKP(4) RKP(5) RKP(6) RKP(7) RKP(8) RKP(9)
    }
    PALLSTORE
  }
}

// Conditional COMPLEX gate on m2, selected by c0 (m1=0): WU_b[n] = W_n*UL_b.
__device__ __forceinline__ void applyWU(cxf* S, const cxf* __restrict__ WUall, int m2, int tid){
  const int sm = (m2==1)?100:((m2==2)?10:1);
  const int ra = (m2==1)?2:1;
  const int rb = (m2==3)?2:3;
  const int sa = (ra==1)?100:10;
  const int sb = (rb==2)?10:1;
  int f = tid;
  if (f < 1000){
    int n = f/100, rem = f-100*n, qa = rem/10, qb = rem-10*qa;
    int base = n*1000 + qa*sa + qb*sb;
    const cxf* __restrict__ U = WUall + n*100;     // transposed complex
    DECL_ACCP
    #pragma unroll 2
    for (int k=0;k<10;k++){
      v2f vv = *(const v2f*)&S[base + k*sm];
      v2f vs = {vv.y, vv.x};
      int kk = k*10;
      CKP(0) CKP(1) CKP(2) CKP(3) CKP(4) CKP(5) CKP(6) CKP(7) CKP(8) CKP(9)
    }
    PALLSTORE
  }
}

// Read-only measure pass: returns sum_i i*|(U v)_i|^2 over this thread's fiber.
__device__ __forceinline__ float measure1(const cxf* S, const cxf* __restrict__ U, int m, int tid){
  const int sm = (m==0)?1000:((m==1)?100:10);
  const int r0 = (m==0)?1:0, r1=(m<=1)?2:1, r2=3;
  const int s0 = (r0==0)?1000:100;
  const int s1 = (r1==1)?100:10;
  const int s2 = 1;
  int f = tid;
  float s = 0.f;
  if (f < 1000){
    int c0=f/100, rem=f-100*c0, c1=rem/10, c2=rem-10*c1;
    int base = c0*s0 + c1*s1 + c2*s2;
    DECL_ACCP
    #pragma unroll 2
    for (int k=0;k<10;k++){
      v2f vv = *(const v2f*)&S[base + k*sm];
      v2f vs = {vv.y, vv.x};
      int kk = k*10;
      CKP(0) CKP(1) CKP(2) CKP(3) CKP(4) CKP(5) CKP(6) CKP(7) CKP(8) CKP(9)
    }
    float p;
    p = a1.x*a1.x + a1.y*a1.y; s += 1.f*p;
    p = a2.x*a2.x + a2.y*a2.y; s += 2.f*p;
    p = a3.x*a3.x + a3.y*a3.y; s += 3.f*p;
    p = a4.x*a4.x + a4.y*a4.y; s += 4.f*p;
    p = a5.x*a5.x + a5.y*a5.y; s += 5.f*p;
    p = a6.x*a6.x + a6.y*a6.y; s += 6.f*p;
    p = a7.x*a7.x + a7.y*a7.y; s += 7.f*p;
    p = a8.x*a8.x + a8.y*a8.y; s += 8.f*p;
    p = a9.x*a9.x + a9.y*a9.y; s += 9.f*p;
  }
  return s;
}

__device__ __forceinline__ void applyBS(cxf* S, const cxf* __restrict__ BSp, int m1, int m2, int tid){
  int ra=-1, rb=-1;
  for (int q=0;q<4;q++) if (q!=m1 && q!=m2){ if (ra<0) ra=q; else rb=q; }
  const int sa = (ra==0)?1000:((ra==1)?100:((ra==2)?10:1));
  const int sb = (rb==0)?1000:((rb==1)?100:((rb==2)?10:1));
  const int s1 = (m1==0)?1000:((m1==1)?100:((m1==2)?10:1));
  const int s2 = (m2==0)?1000:((m2==1)?100:((m2==2)?10:1));
  const int ds = s1 - s2;
  #pragma unroll 1
  for (int w0=0; w0<2048; w0+=NTB){
    int it = w0 + tid;
    if (it < 1900){
      int bn = it/100, rest = it-100*bn;
      int ilo = bn<10?0:bn-9, ihi = bn<10?bn:9, sz = ihi-ilo+1;
      int ca = rest/10, cb = rest-10*ca;
      int base = ca*sa + cb*sb;
      const cxf* __restrict__ Bt = BSp + bn*100;   // transposed
      DECL_ACCP
      int radr = base + ilo*s1 + (bn-ilo)*s2;
      int kk = 0;
      #pragma unroll 1
      for (int c=0;c<sz;c++){
        v2f vv = *(const v2f*)&S[radr];
        v2f vs = {vv.y, vv.x};
        BKP(0) BKP(1) BKP(2) BKP(3) BKP(4) BKP(5) BKP(6) BKP(7) BKP(8) BKP(9)
        radr += ds; kk += 10;
      }
      int wadr = base + ilo*s1 + (bn-ilo)*s2;
      BPALLSTORE
    }
  }
}

__global__ __launch_bounds__(NTB)
__attribute__((amdgpu_waves_per_eu(8)))
void state_kernel(const float* __restrict__ wd, const float* __restrict__ bd,
                  const float* __restrict__ wsf, float* __restrict__ out){
  extern __shared__ __align__(16) char smem[];
  cxf* S    = (cxf*)smem;                 // 10000 cxf (80000 B)
  cxf* uv   = (cxf*)(smem + 80000);       // 4*10 encoding vectors
  float* red = (float*)(smem + 80320);    // 16

  const float* __restrict__ V   = wsf;            // for V^T gate
  const float* __restrict__ VT  = wsf + 100;      // for V gate
  const float* __restrict__ W   = wsf + 200;
  const cxf*   __restrict__ BSm = (const cxf*)(wsf + 1200);
  const cxf*   __restrict__ UL  = (const cxf*)(wsf + 5000);
  const cxf*   __restrict__ WU  = (const cxf*)(wsf + 9800);
  const cxf*   __restrict__ uw  = (const cxf*)(wsf + U_OFF);

  const int tid = threadIdx.x, wv = tid>>6, lane = tid&63;
  const int b = blockIdx.x;

  if (tid < 40) uv[tid] = uw[b*40 + tid];
  __syncthreads();

  // Init: product state S = u0 (x) u1 (x) u2 (x) u3  (L0's V0^T folded in u0)
  for (int e=tid; e<10000; e+=NTB){
    int c0=e/1000, r_=e-1000*c0, c1=r_/100, r2_=r_-100*c1, c2=r2_/10, c3=r2_-10*c2;
    cxf A = uv[c0], B = uv[10+c1], C = uv[20+c2], D = uv[30+c3];
    float pr = A.x*B.x - A.y*B.y, pi = A.x*B.y + A.y*B.x;
    float qr = pr*C.x - pi*C.y,  qi = pr*C.y + pi*C.x;
    cxf o; o.x = qr*D.x - qi*D.y; o.y = qr*D.y + qi*D.x;
    S[e] = o;
  }
  __syncthreads();

  // ---------------- Layer 0 ----------------
  applyW(S, W, 0, 1, tid); __syncthreads();
  applyW(S, W, 0, 2, tid); __syncthreads();
  applyW(S, W, 0, 3, tid); __syncthreads();
  apply1_r(S, VT, 0, tid); __syncthreads();      // V0
  apply1_r(S, V, 1, tid);  __syncthreads();      // V1^T
  applyW(S, W, 1, 2, tid); __syncthreads();
  applyW(S, W, 1, 3, tid); __syncthreads();
  apply1_r(S, VT, 1, tid); __syncthreads();      // V1
  apply1_r(S, V, 2, tid);  __syncthreads();      // V2^T
  applyW(S, W, 2, 3, tid); __syncthreads();
  apply1_r(S, VT, 2, tid); __syncthreads();      // V2
  applyBS(S, BSm, 0, 1, tid); __syncthreads();
  applyBS(S, BSm, 1, 2, tid); __syncthreads();
  applyBS(S, BSm, 2, 3, tid); __syncthreads();
  applyBS(S, BSm, 3, 0, tid); __syncthreads();
  apply1_c(S, UL, 0, tid); __syncthreads();      // UL0_L0 (carries L1's V0^T)

  // ---------------- Layer 1 ----------------
  applyWU(S, WU,        1, tid); __syncthreads();
  applyWU(S, WU + 1000, 2, tid); __syncthreads();
  applyWU(S, WU + 2000, 3, tid); __syncthreads();
  apply1_r(S, VT, 0, tid); __syncthreads();      // V0
  apply1_r(S, V, 1, tid);  __syncthreads();      // V1^T
  applyW(S, W, 1, 2, tid); __syncthreads();
  applyW(S, W, 1, 3, tid); __syncthreads();
  apply1_r(S, VT, 1, tid); __syncthreads();      // V1
  apply1_r(S, V, 2, tid);  __syncthreads();      // V2^T
  applyW(S, W, 2, 3, tid); __syncthreads();
  apply1_r(S, VT, 2, tid); __syncthreads();      // V2
  applyBS(S, BSm, 0, 1, tid); __syncthreads();
  applyBS(S, BSm, 1, 2, tid); __syncthreads();
  applyBS(S, BSm, 2, 3, tid); __syncthreads();
  applyBS(S, BSm, 3, 0, tid); __syncthreads();

  // Fused measurement (UL[L1,3] dropped; read-only passes, no barriers).
  float w0 = wd[0], w1 = wd[1], w2 = wd[2];
  float acc = 0.f;
  acc += w0 * measure1(S, UL + 400, 0, tid);
  acc += w1 * measure1(S, UL + 500, 1, tid);
  acc += w2 * measure1(S, UL + 600, 2, tid);

  for (int off=32; off; off>>=1) acc += __shfl_down(acc, off, 64);
  if (lane == 0) red[wv] = acc;
  __syncthreads();
  if (tid == 0){
    float s = 0.f;
    for (int i=0;i<16;i++) s += red[i];
    out[b] = s + bd[0];
  }
}

} // anonymous namespace

extern "C" void kernel_launch(void* const* d_in, const int* in_sizes, int n_in,
                              void* d_out, int out_size, void* d_ws, size_t ws_size,
                              hipStream_t stream){
  const float* jets   = (const float*)d_in[0];
  const float* sscale = (const float*)d_in[1];
  const float* dmag   = (const float*)d_in[2];
  const float* dphase = (const float*)d_in[3];
  const float* smag   = (const float*)d_in[4];
  const float* sphase = (const float*)d_in[5];
  const float* wd     = (const float*)d_in[6];
  const float* bd     = (const float*)d_in[7];
  float* out = (float*)d_out;
  float* wsf = (float*)d_ws;
  int B = in_sizes[0] / 12;

  (void)hipFuncSetAttribute(reinterpret_cast<const void*>(&state_kernel),
                            hipFuncAttributeMaxDynamicSharedMemorySize, SMEM_BYTES);

  gates_kernel<<<12, 256, 0, stream>>>(dmag, dphase, smag, sphase, wsf);
  fuse_kernel<<<1, 512, 0, stream>>>(wsf);
  enc_kernel<<<B*4, 128, 0, stream>>>(jets, sscale, wsf);
  state_kernel<<<B, NTB, SMEM_BYTES, stream>>>(wd, bd, wsf, out);
}